// Round 4
// baseline (1752.953 us; speedup 1.0000x reference)
//
#include <hip/hip_runtime.h>
#include <cstdint>
#include <cstddef>

#define B_ 4096
#define T_ 128
#define N_ 128
#define H_ 128
#define G4_ 512       // 4*H
#define KC_ 256       // concat K = [x|h]
#define EPS_ 1e-5f

#define RPB_ 16       // batch rows per block
#define NB_ 256       // blocks (one per CU)
#define W0K_ 128      // layer0 K-half staged in LDS (k = 0..127, the x-part)
#define W0P_ 136      // W0l LDS stride (f16): 272 B (v2-proven layout)
#define APAD_ 264     // A-tile LDS stride (f16): 528 B (v2-proven layout)

typedef _Float16 f16x8 __attribute__((ext_vector_type(8)));
typedef _Float16 f16x4 __attribute__((ext_vector_type(4)));
typedef float f32x4 __attribute__((ext_vector_type(4)));

__device__ __forceinline__ float sigm_(float x) { return 1.f / (1.f + __expf(-x)); }
__device__ __forceinline__ float tanh_(float x) {
  float ax = fabsf(x);
  float e = __expf(-2.f * ax);
  float t = (1.f - e) / (1.f + e);
  return copysignf(t, x);
}

// raw barrier: LDS visibility only — NO vmcnt(0) drain (out1 stores / prefetches
// keep flowing across it). All in-loop cross-wave deps are LDS-only.
#define LBAR() asm volatile("s_waitcnt lgkmcnt(0)\n\ts_barrier" ::: "memory")

#define MFMA16(a, b, c) __builtin_amdgcn_mfma_f32_16x16x32_f16((a), (b), (c), 0, 0, 0)

// ---------------- K0: pack weights to f16 [2][512][256] = [Wih | Whh], combine biases, zero stats
__global__ void k0_prep(const float* __restrict__ Wih0, const float* __restrict__ Whh0,
                        const float* __restrict__ bih0, const float* __restrict__ bhh0,
                        const float* __restrict__ Wih1, const float* __restrict__ Whh1,
                        const float* __restrict__ bih1, const float* __restrict__ bhh1,
                        _Float16* __restrict__ Wpack, float* __restrict__ bpack,
                        float* __restrict__ sumb, float* __restrict__ sqb) {
  int idx = blockIdx.x * blockDim.x + threadIdx.x;
  if (idx < 2 * G4_ * KC_) {
    int k = idx & (KC_ - 1);
    int j = (idx >> 8) & (G4_ - 1);
    int l = idx >> 17;
    const float* Wih = l ? Wih1 : Wih0;
    const float* Whh = l ? Whh1 : Whh0;
    float v = (k < N_) ? Wih[j * N_ + k] : Whh[j * N_ + (k - N_)];
    Wpack[idx] = (_Float16)v;
  }
  if (idx < 2 * G4_) {
    int j = idx & (G4_ - 1);
    bpack[idx] = (idx >> 9) ? (bih1[j] + bhh1[j]) : (bih0[j] + bhh0[j]);
  }
  if (idx < T_ * N_) { sumb[idx] = 0.f; sqb[idx] = 0.f; }
}

// ---------------- K1: score_x + softmax over n -> alpha[b][n]  (time-invariant)
__global__ void k1_alpha(const float* __restrict__ X, const float* __restrict__ attn_w,
                         const float* __restrict__ attn_b, float* __restrict__ alpha) {
  __shared__ float xs[T_ * N_];  // 64 KB
  __shared__ float wx[T_];
  __shared__ float ps[2][N_];
  __shared__ float red[8];
  int b = blockIdx.x;
  int tid = threadIdx.x;  // 0..255
  if (tid < T_) wx[tid] = attn_w[2 * H_ + tid];
  const float* xb = X + (size_t)b * T_ * N_;
#pragma unroll
  for (int i = 0; i < 16; ++i) {
    int fi = ((i << 8) + tid) << 2;
    *(f32x4*)&xs[fi] = *(const f32x4*)&xb[fi];
  }
  __syncthreads();
  int n = tid & 127, hf = tid >> 7;
  float s = 0.f;
  {
    int t0 = hf << 6;
#pragma unroll 8
    for (int tt = 0; tt < 64; ++tt) s = fmaf(xs[(t0 + tt) * N_ + n], wx[t0 + tt], s);
  }
  ps[hf][n] = s;
  __syncthreads();
  s = ps[0][n] + ps[1][n] + attn_b[0];
  float m = s;
#pragma unroll
  for (int off = 32; off >= 1; off >>= 1) m = fmaxf(m, __shfl_xor(m, off));
  int wv = tid >> 6;
  if ((tid & 63) == 0) red[wv] = m;
  __syncthreads();
  m = fmaxf(red[0], red[1]);
  float e = __expf(s - m);
  float sm = e;
#pragma unroll
  for (int off = 32; off >= 1; off >>= 1) sm += __shfl_xor(sm, off);
  if ((tid & 63) == 0) red[4 + wv] = sm;
  __syncthreads();
  sm = red[4] + red[5];
  if (hf == 0) alpha[b * N_ + n] = e / sm;
}

// ---------------- K2: X_tilde = alpha*X (write output 0) + BN partial stats per (t,n)
__global__ void k2_xtilde(const float* __restrict__ X, const float* __restrict__ alpha,
                          float* __restrict__ out0, float* __restrict__ sumb,
                          float* __restrict__ sqb) {
  int t = blockIdx.x;
  int chunk = blockIdx.y;
  int tid = threadIdx.x;         // 0..255
  int c = (tid & 31) << 2;       // 0..124
  int r = tid >> 5;              // 0..7
  f32x4 s4 = {}, q4 = {};
#pragma unroll 4
  for (int it = 0; it < 32; ++it) {
    int b = (chunk << 8) + (it << 3) + r;
    f32x4 a4 = *(const f32x4*)&alpha[b * N_ + c];
    size_t off = ((size_t)b * T_ + t) * N_ + c;
    f32x4 x4 = *(const f32x4*)&X[off];
    f32x4 v;
#pragma unroll
    for (int e = 0; e < 4; ++e) v[e] = a4[e] * x4[e];
    *(f32x4*)&out0[off] = v;
#pragma unroll
    for (int e = 0; e < 4; ++e) { s4[e] += v[e]; q4[e] += v[e] * v[e]; }
  }
  __shared__ float ps[8][N_], pq[8][N_];
  *(f32x4*)&ps[r][c] = s4;
  *(f32x4*)&pq[r][c] = q4;
  __syncthreads();
  if (tid < N_) {
    float s = 0.f, q = 0.f;
#pragma unroll
    for (int rr = 0; rr < 8; ++rr) { s += ps[rr][tid]; q += pq[rr][tid]; }
    atomicAdd(&sumb[t * N_ + tid], s);
    atomicAdd(&sqb[t * N_ + tid], q);
  }
}

// ---------------- K3: finalize BN -> per-(t,n) scale/shift
__global__ void k3_finalize(const float* __restrict__ sumb, const float* __restrict__ sqb,
                            const float* __restrict__ gamma, const float* __restrict__ beta,
                            float* __restrict__ scale, float* __restrict__ shift) {
  int i = blockIdx.x * blockDim.x + threadIdx.x;
  if (i >= T_ * N_) return;
  int n = i & (N_ - 1);
  float mean = sumb[i] * (1.f / B_);
  float var = sqb[i] * (1.f / B_) - mean * mean;
  float rstd = rsqrtf(var + EPS_);
  float g = gamma[n];
  scale[i] = rstd * g;
  shift[i] = beta[n] - mean * rstd * g;
}

// ---------------- K4: 2-layer LSTM recurrence, v4.
// = v2 structure (kb-outer/g-inner MFMA, single-buffered A-tiles, 4 barriers) +
//   volatile-resident w1 (AGPR) + staggered early W0h stream + LDS-only raw barriers
//   (no vmcnt drain) + bias-in-acc-init.
__global__ __launch_bounds__(512, 2) void k4_recur(
    const float* __restrict__ xt /* X_tilde */, const _Float16* __restrict__ Wpack,
    const float* __restrict__ bpack, const float* __restrict__ scale,
    const float* __restrict__ shift, float* __restrict__ out1) {
  __shared__ _Float16 W0l[G4_][W0P_];  // 139264 B (x-half of W0)
  __shared__ _Float16 A0[RPB_][APAD_]; // [xb | h0]   8448 B
  __shared__ _Float16 A1[RPB_][APAD_]; // [h0n | h1]  8448 B  -> total 156160 B

  const int tid = threadIdx.x;
  const int w = tid >> 6;
  const int lane = tid & 63;
  const int quad = lane >> 4;
  const int l16 = lane & 15;
  const int nb = blockIdx.x;
  const int col = (w << 4) + l16;  // output col owned by this lane

  // ---- one-time: stage W0 x-half into LDS (thread t copies row t)
  {
    const _Float16* src = Wpack + (size_t)tid * KC_;
#pragma unroll
    for (int kk = 0; kk < W0K_; kk += 8)
      *(f16x8*)&W0l[tid][kk] = *(const f16x8*)&src[kk];
  }

  // ---- layer-1 weights resident (volatile -> cannot remat; lands in AGPRs)
  f16x8 w1[4][8];
#pragma unroll
  for (int g = 0; g < 4; ++g) {
    const _Float16* src = Wpack + (size_t)(G4_ + (g << 7) + col) * KC_ + (quad << 3);
#pragma unroll
    for (int kb = 0; kb < 8; ++kb)
      w1[g][kb] = *(volatile const f16x8*)&src[kb << 5];
  }

  float bia0[4], bia1[4];
#pragma unroll
  for (int g = 0; g < 4; ++g) {
    bia0[g] = bpack[(g << 7) + col];
    bia1[g] = bpack[G4_ + (g << 7) + col];
  }

  float c0[4], c1[4];
#pragma unroll
  for (int e = 0; e < 4; ++e) { c0[e] = 0.f; c1[e] = 0.f; }

  // staging coords: each thread stages 4 floats of one row
  const int sr = tid >> 5;          // 0..15
  const int sc = (tid & 31) << 2;   // 0..124
  const size_t browbase = (size_t)(nb * RPB_ + sr) * T_;

  // prologue: stage xb(0), zero h-halves
  {
    f32x4 xv = *(const f32x4*)(xt + (browbase + 0) * N_ + sc);
    f32x4 s4 = *(const f32x4*)(scale + sc);
    f32x4 h4 = *(const f32x4*)(shift + sc);
    f16x4 hv;
#pragma unroll
    for (int e = 0; e < 4; ++e) hv[e] = (_Float16)fmaf(xv[e], s4[e], h4[e]);
    *(f16x4*)&A0[sr][sc] = hv;
    f16x4 z4 = {};
    *(f16x4*)&A0[sr][N_ + sc] = z4;
    *(f16x4*)&A1[sr][N_ + sc] = z4;
  }
  LBAR();

  for (int t = 0; t < T_; ++t) {
    // opaque zero: pins streamed-load issue inside the loop (blocks LICM hoist)
    int zz = 0;
    asm volatile("" : "+v"(zz));

    // ---- GEMM0: gates0 = [xb|h0] @ W0^T + b0 (bias as acc init)
    f32x4 acc[4];
#pragma unroll
    for (int g = 0; g < 4; ++g) acc[g] = (f32x4){bia0[g], bia0[g], bia0[g], bia0[g]};

    // issue streamed W0h kb=4,5 early (consumed after kb0..3 ≈ 300+ cy later)
    f16x8 sb[4][4];
#pragma unroll
    for (int g = 0; g < 4; ++g) {
      const _Float16* wp =
          Wpack + (size_t)((g << 7) + col) * KC_ + W0K_ + (quad << 3) + zz;
      sb[g][0] = *(const f16x8*)&wp[0];
      sb[g][1] = *(const f16x8*)&wp[32];
    }
    // kb 0..1 from LDS (x-half)
#pragma unroll
    for (int kb = 0; kb < 2; ++kb) {
      f16x8 a = *(const f16x8*)&A0[l16][(kb << 5) + (quad << 3)];
#pragma unroll
      for (int g = 0; g < 4; ++g) {
        f16x8 bf = *(const f16x8*)&W0l[(g << 7) + col][(kb << 5) + (quad << 3)];
        acc[g] = MFMA16(a, bf, acc[g]);
      }
    }
    // issue streamed W0h kb=6,7
#pragma unroll
    for (int g = 0; g < 4; ++g) {
      const _Float16* wp =
          Wpack + (size_t)((g << 7) + col) * KC_ + W0K_ + 64 + (quad << 3) + zz;
      sb[g][2] = *(const f16x8*)&wp[0];
      sb[g][3] = *(const f16x8*)&wp[32];
    }
    // prefetch next-step x/scale/shift AFTER weight streams (in-order vmcnt:
    // waiting on sb never waits on these)
    f32x4 xn = {}, scn = {}, shn = {};
    if (t + 1 < T_) {
      xn = *(const f32x4*)(xt + (browbase + t + 1) * N_ + sc);
      scn = *(const f32x4*)(scale + (t + 1) * N_ + sc);
      shn = *(const f32x4*)(shift + (t + 1) * N_ + sc);
    }
    // kb 2..3 from LDS
#pragma unroll
    for (int kb = 2; kb < 4; ++kb) {
      f16x8 a = *(const f16x8*)&A0[l16][(kb << 5) + (quad << 3)];
#pragma unroll
      for (int g = 0; g < 4; ++g) {
        f16x8 bf = *(const f16x8*)&W0l[(g << 7) + col][(kb << 5) + (quad << 3)];
        acc[g] = MFMA16(a, bf, acc[g]);
      }
    }
    // kb 4..7 from streamed regs (h-half)
#pragma unroll
    for (int kb = 4; kb < 8; ++kb) {
      f16x8 a = *(const f16x8*)&A0[l16][(kb << 5) + (quad << 3)];
#pragma unroll
      for (int g = 0; g < 4; ++g) acc[g] = MFMA16(a, sb[g][kb - 4], acc[g]);
    }

    // ---- act0 (register-only; acc row = quad*4+e, col = lane's col)
    _Float16 h0h[4];
#pragma unroll
    for (int e = 0; e < 4; ++e) {
      float ig = acc[0][e];
      float fg = acc[1][e];
      float gg = acc[2][e];
      float og = acc[3][e];
      float cn = sigm_(fg) * c0[e] + sigm_(ig) * tanh_(gg);
      c0[e] = cn;
      h0h[e] = (_Float16)(sigm_(og) * tanh_(cn));
    }
    LBAR();  // #1: all waves' GEMM0 LDS reads complete
#pragma unroll
    for (int e = 0; e < 4; ++e) {
      A0[(quad << 2) + e][N_ + col] = h0h[e];  // h0 for next step's GEMM0
      A1[(quad << 2) + e][col] = h0h[e];       // h0n for this step's GEMM1
    }
    LBAR();  // #2: A1 low half (and A0 high) visible

    // ---- GEMM1: gates1 = [h0n|h1] @ W1^T + b1 ; B from resident registers
    f32x4 acc1[4];
#pragma unroll
    for (int g = 0; g < 4; ++g) acc1[g] = (f32x4){bia1[g], bia1[g], bia1[g], bia1[g]};
#pragma unroll
    for (int kb = 0; kb < 8; ++kb) {
      f16x8 a = *(const f16x8*)&A1[l16][(kb << 5) + (quad << 3)];
#pragma unroll
      for (int g = 0; g < 4; ++g) acc1[g] = MFMA16(a, w1[g][kb], acc1[g]);
    }

    // ---- act1 + output store (stores retire across the next barriers)
    _Float16 h1h[4];
#pragma unroll
    for (int e = 0; e < 4; ++e) {
      float ig = acc1[0][e];
      float fg = acc1[1][e];
      float gg = acc1[2][e];
      float og = acc1[3][e];
      float cn = sigm_(fg) * c1[e] + sigm_(ig) * tanh_(gg);
      c1[e] = cn;
      float hn = sigm_(og) * tanh_(cn);
      h1h[e] = (_Float16)hn;
      out1[((size_t)(nb * RPB_ + (quad << 2) + e) * T_ + t) * H_ + col] = hn;
    }
    LBAR();  // #3: all waves' GEMM1 LDS reads complete
#pragma unroll
    for (int e = 0; e < 4; ++e)
      A1[(quad << 2) + e][N_ + col] = h1h[e];  // h1 for next step's GEMM1
    if (t + 1 < T_) {  // stage xb(t+1) (A0 low reads finished before #1)
      f16x4 hv;
#pragma unroll
      for (int e = 0; e < 4; ++e) hv[e] = (_Float16)fmaf(xn[e], scn[e], shn[e]);
      *(f16x4*)&A0[sr][sc] = hv;
    }
    LBAR();  // #4: all tiles ready for next step
  }
}

extern "C" void kernel_launch(void* const* d_in, const int* in_sizes, int n_in,
                              void* d_out, int out_size, void* d_ws, size_t ws_size,
                              hipStream_t stream) {
  const float* X = (const float*)d_in[0];
  const float* attnw = (const float*)d_in[1];
  const float* attnb = (const float*)d_in[2];
  const float* gamma = (const float*)d_in[3];
  const float* beta = (const float*)d_in[4];
  const float* Wih0 = (const float*)d_in[5];
  const float* Whh0 = (const float*)d_in[6];
  const float* bih0 = (const float*)d_in[7];
  const float* bhh0 = (const float*)d_in[8];
  const float* Wih1 = (const float*)d_in[9];
  const float* Whh1 = (const float*)d_in[10];
  const float* bih1 = (const float*)d_in[11];
  const float* bhh1 = (const float*)d_in[12];

  float* out0 = (float*)d_out;                    // X_tilde
  float* out1 = out0 + (size_t)B_ * T_ * N_;      // X_encoded

  float* ws = (float*)d_ws;
  float* alpha = ws;                              // B*N
  float* sumb = alpha + (size_t)B_ * N_;          // T*N
  float* sqb = sumb + T_ * N_;
  float* scale = sqb + T_ * N_;
  float* shift = scale + T_ * N_;
  float* bpack = shift + T_ * N_;                 // 2*512
  _Float16* Wpack = (_Float16*)(bpack + 2 * G4_); // 2*512*256 f16 (16B-aligned)

  k0_prep<<<1024, 256, 0, stream>>>(Wih0, Whh0, bih0, bhh0, Wih1, Whh1, bih1, bhh1,
                                    Wpack, bpack, sumb, sqb);
  k1_alpha<<<B_, 256, 0, stream>>>(X, attnw, attnb, alpha);
  k2_xtilde<<<dim3(T_, 16), 256, 0, stream>>>(X, alpha, out0, sumb, sqb);
  k3_finalize<<<64, 256, 0, stream>>>(sumb, sqb, gamma, beta, scale, shift);
  k4_recur<<<NB_, 512, 0, stream>>>(out0, Wpack, bpack, scale, shift, out1);
}

// Round 5
// 1385.003 us; speedup vs baseline: 1.2657x; 1.2657x over previous
//
#include <hip/hip_runtime.h>
#include <cstdint>
#include <cstddef>

#define B_ 4096
#define T_ 128
#define N_ 128
#define H_ 128
#define G4_ 512       // 4*H
#define KC_ 256       // concat K = [x|h]
#define EPS_ 1e-5f

#define RPB_ 16       // batch rows per block (k4)
#define NB_ 256       // k4 blocks (one per CU)
#define W0K_ 128      // layer0 K-half staged in LDS (k = 0..127, the x-part)
#define W0P_ 136      // W0l LDS stride (f16)

#define KB_ 512       // k12 blocks
#define ROWS_ 8       // b-rows per k12 block
#define PSBLK_ 16384  // floats per block partial: 2*64*128

typedef _Float16 f16x8 __attribute__((ext_vector_type(8)));
typedef _Float16 f16x4 __attribute__((ext_vector_type(4)));
typedef float f32x4 __attribute__((ext_vector_type(4)));

__device__ __forceinline__ float sigm_(float x) { return 1.f / (1.f + __expf(-x)); }
__device__ __forceinline__ float tanh_(float x) {
  float ax = fabsf(x);
  float e = __expf(-2.f * ax);
  float t = (1.f - e) / (1.f + e);
  return copysignf(t, x);
}

// ---------------- K0: pack weights to f16 [2][512][256] = [Wih | Whh], combine biases
__global__ void k0_prep(const float* __restrict__ Wih0, const float* __restrict__ Whh0,
                        const float* __restrict__ bih0, const float* __restrict__ bhh0,
                        const float* __restrict__ Wih1, const float* __restrict__ Whh1,
                        const float* __restrict__ bih1, const float* __restrict__ bhh1,
                        _Float16* __restrict__ Wpack, float* __restrict__ bpack) {
  int idx = blockIdx.x * blockDim.x + threadIdx.x;
  if (idx < 2 * G4_ * KC_) {
    int k = idx & (KC_ - 1);
    int j = (idx >> 8) & (G4_ - 1);
    int l = idx >> 17;
    const float* Wih = l ? Wih1 : Wih0;
    const float* Whh = l ? Whh1 : Whh0;
    float v = (k < N_) ? Wih[j * N_ + k] : Whh[j * N_ + (k - N_)];
    Wpack[idx] = (_Float16)v;
  }
  if (idx < 2 * G4_) {
    int j = idx & (G4_ - 1);
    bpack[idx] = (idx >> 9) ? (bih1[j] + bhh1[j]) : (bih0[j] + bhh0[j]);
  }
}

// ---------------- K12: fused alpha (softmax over n) + X_tilde + BN partial stats.
// 512 blocks x 8 b-rows. Per row: stage X[b] (64 KB) to LDS once; score from LDS;
// softmax; x_tilde from LDS (X read ONCE from HBM); per-thread reg partials.
// Partials ps[blk][th][tt][n] written non-atomically; reduced by k3r.
__global__ __launch_bounds__(256, 2) void k12_fused(
    const float* __restrict__ X, const float* __restrict__ attn_w,
    const float* __restrict__ attn_b, float* __restrict__ out0,
    float* __restrict__ psum, float* __restrict__ psq) {
  __shared__ float xs[T_ * N_];  // 64 KB
  __shared__ float wx[T_];
  __shared__ float redS[2][N_];
  __shared__ float redM[4], redE[4];
  const int tid = threadIdx.x;  // 0..255
  const int blk = blockIdx.x;   // 0..511
  const int n = tid & 127;
  const int th = tid >> 7;      // t-half 0/1
  const int wv = tid >> 6;      // wave 0..3 (0,1: th=0 n=0..63/64..127; 2,3: th=1 dups)
  if (tid < T_) wx[tid] = attn_w[2 * H_ + tid];
  const float ab = attn_b[0];
  float sum[64], sq[64];
#pragma unroll
  for (int i = 0; i < 64; ++i) { sum[i] = 0.f; sq[i] = 0.f; }

  for (int rb = 0; rb < ROWS_; ++rb) {
    const int b = blk * ROWS_ + rb;
    const float* xb = X + (size_t)b * T_ * N_;
    __syncthreads();  // xs free (prev row's readers done)
#pragma unroll
    for (int i = 0; i < 16; ++i) {
      int fi = ((i << 8) + tid) << 2;
      *(f32x4*)&xs[fi] = *(const f32x4*)&xb[fi];
    }
    __syncthreads();
    // score: column-dot over this thread's t-half
    float s = 0.f;
#pragma unroll 8
    for (int tt = 0; tt < 64; ++tt) {
      int t = (th << 6) + tt;
      s = fmaf(xs[t * N_ + n], wx[t], s);
    }
    redS[th][n] = s;
    __syncthreads();
    s = redS[0][n] + redS[1][n] + ab;
    // softmax over n (waves 2,3 duplicate waves 0,1 -> max over all 4 ok; sum uses 0+1)
    float m = s;
#pragma unroll
    for (int off = 32; off >= 1; off >>= 1) m = fmaxf(m, __shfl_xor(m, off));
    if ((tid & 63) == 0) redM[wv] = m;
    __syncthreads();
    m = fmaxf(fmaxf(redM[0], redM[1]), fmaxf(redM[2], redM[3]));
    float e = __expf(s - m);
    float sm = e;
#pragma unroll
    for (int off = 32; off >= 1; off >>= 1) sm += __shfl_xor(sm, off);
    if ((tid & 63) == 0) redE[wv] = sm;
    __syncthreads();
    sm = redE[0] + redE[1];
    const float alpha = e / sm;
    // x_tilde + stats (sum/sq fully unrolled -> static reg indexing)
    const size_t obase = ((size_t)b * T_ + (th << 6)) * N_ + n;
#pragma unroll
    for (int tt = 0; tt < 64; ++tt) {
      float v = alpha * xs[((th << 6) + tt) * N_ + n];
      sum[tt] += v;
      sq[tt] += v * v;
      out0[obase + (size_t)tt * N_] = v;
    }
  }
  // write partials: ps[blk][th][tt][n]
  float* pbs = psum + (size_t)blk * PSBLK_ + th * 8192 + n;
  float* pbq = psq + (size_t)blk * PSBLK_ + th * 8192 + n;
#pragma unroll
  for (int tt = 0; tt < 64; ++tt) {
    pbs[tt * 128] = sum[tt];
    pbq[tt * 128] = sq[tt];
  }
}

// ---------------- K3r: reduce partials over 512 blocks -> per-(t,n) scale/shift
__global__ void k3r(const float* __restrict__ psum, const float* __restrict__ psq,
                    const float* __restrict__ gamma, const float* __restrict__ beta,
                    float* __restrict__ scale, float* __restrict__ shift) {
  const int t = blockIdx.x;    // 0..127
  const int n = threadIdx.x;   // 0..127
  const int th = t >> 6, tt = t & 63;
  const size_t off = (size_t)th * 8192 + tt * 128 + n;
  float s = 0.f, q = 0.f;
  for (int blk = 0; blk < KB_; ++blk) {
    s += psum[(size_t)blk * PSBLK_ + off];
    q += psq[(size_t)blk * PSBLK_ + off];
  }
  float mean = s * (1.f / B_);
  float var = q * (1.f / B_) - mean * mean;
  float rstd = rsqrtf(var + EPS_);
  float g = gamma[n];
  scale[t * N_ + n] = rstd * g;
  shift[t * N_ + n] = beta[n] - mean * rstd * g;
}

// ---------------- K4: 2-layer LSTM recurrence — EXACT v2 (round-2, 756 µs).
// 256 blocks x 16 rows, 8 waves. Wave w owns output cols [w*16,w*16+16), all 4 gates
// (register-only activations). Layer-1 weights: plain loads, compiler remat/pipelines
// from L2 (empirically faster than forced residency). W0 x-half in LDS; h-half inline.
__global__ __launch_bounds__(512, 2) void k4_recur(
    const float* __restrict__ xt /* X_tilde */, const _Float16* __restrict__ Wpack,
    const float* __restrict__ bpack, const float* __restrict__ scale,
    const float* __restrict__ shift, float* __restrict__ out1) {
  __shared__ _Float16 W0l[G4_][W0P_];  // 139264 B
  __shared__ _Float16 A0[RPB_][264];   // [xb | h0], 8448 B
  __shared__ _Float16 A1[RPB_][264];   // [h0n | h1], 8448 B   (total 156160 B)

  const int tid = threadIdx.x;
  const int w = tid >> 6;
  const int lane = tid & 63;
  const int quad = lane >> 4;
  const int l16 = lane & 15;
  const int nb = blockIdx.x;
  const int col = (w << 4) + l16;

  {
    const _Float16* src = Wpack + (size_t)tid * KC_;
#pragma unroll
    for (int kk = 0; kk < W0K_; kk += 8)
      *(f16x8*)&W0l[tid][kk] = *(const f16x8*)&src[kk];
  }

  f16x8 w1[4][8];
#pragma unroll
  for (int g = 0; g < 4; ++g) {
    const _Float16* src = Wpack + (size_t)(G4_ + (g << 7) + col) * KC_ + (quad << 3);
#pragma unroll
    for (int kb = 0; kb < 8; ++kb) w1[g][kb] = *(const f16x8*)&src[kb << 5];
  }

  float bia0[4], bia1[4];
#pragma unroll
  for (int g = 0; g < 4; ++g) {
    bia0[g] = bpack[(g << 7) + col];
    bia1[g] = bpack[G4_ + (g << 7) + col];
  }

  float c0[4], c1[4];
#pragma unroll
  for (int e = 0; e < 4; ++e) { c0[e] = 0.f; c1[e] = 0.f; }

  const int sr = tid >> 5;
  const int sc = (tid & 31) << 2;
  const size_t browbase = (size_t)(nb * RPB_ + sr) * T_;

  {
    f32x4 xv = *(const f32x4*)(xt + (browbase + 0) * N_ + sc);
    f32x4 s4 = *(const f32x4*)(scale + sc);
    f32x4 h4 = *(const f32x4*)(shift + sc);
    f16x4 hv;
#pragma unroll
    for (int e = 0; e < 4; ++e) hv[e] = (_Float16)fmaf(xv[e], s4[e], h4[e]);
    *(f16x4*)&A0[sr][sc] = hv;
    f16x4 z = {};
    *(f16x4*)&A0[sr][N_ + sc] = z;
    *(f16x4*)&A1[sr][N_ + sc] = z;
  }
  __syncthreads();

  for (int t = 0; t < T_; ++t) {
    f32x4 xn = {};
    if (t + 1 < T_) xn = *(const f32x4*)(xt + (browbase + t + 1) * N_ + sc);

    f32x4 acc[4] = {};
#pragma unroll
    for (int kb = 0; kb < 8; ++kb) {
      f16x8 a = *(const f16x8*)&A0[l16][(kb << 5) + (quad << 3)];
      if (kb < 4) {
#pragma unroll
        for (int g = 0; g < 4; ++g) {
          f16x8 bf = *(const f16x8*)&W0l[(g << 7) + col][(kb << 5) + (quad << 3)];
          acc[g] = __builtin_amdgcn_mfma_f32_16x16x32_f16(a, bf, acc[g], 0, 0, 0);
        }
      } else {
#pragma unroll
        for (int g = 0; g < 4; ++g) {
          f16x8 bf = *(const f16x8*)(Wpack + (size_t)((g << 7) + col) * KC_ +
                                     (kb << 5) + (quad << 3));
          acc[g] = __builtin_amdgcn_mfma_f32_16x16x32_f16(a, bf, acc[g], 0, 0, 0);
        }
      }
    }

    _Float16 h0h[4];
#pragma unroll
    for (int e = 0; e < 4; ++e) {
      float ig = acc[0][e] + bia0[0];
      float fg = acc[1][e] + bia0[1];
      float gg = acc[2][e] + bia0[2];
      float og = acc[3][e] + bia0[3];
      float cn = sigm_(fg) * c0[e] + sigm_(ig) * tanh_(gg);
      c0[e] = cn;
      h0h[e] = (_Float16)(sigm_(og) * tanh_(cn));
    }
    __syncthreads();  // #1
#pragma unroll
    for (int e = 0; e < 4; ++e) {
      A0[(quad << 2) + e][N_ + col] = h0h[e];
      A1[(quad << 2) + e][col] = h0h[e];
    }
    __syncthreads();  // #2

    f16x8 a1[8];
#pragma unroll
    for (int kb = 0; kb < 4; ++kb) {
      a1[kb] = *(const f16x8*)&A1[l16][(kb << 5) + (quad << 3)];
      a1[4 + kb] = *(const f16x8*)&A1[l16][128 + (kb << 5) + (quad << 3)];
    }
    f32x4 acc1[4] = {};
#pragma unroll
    for (int kb = 0; kb < 8; ++kb) {
#pragma unroll
      for (int g = 0; g < 4; ++g)
        acc1[g] = __builtin_amdgcn_mfma_f32_16x16x32_f16(a1[kb], w1[g][kb], acc1[g], 0, 0, 0);
    }

    _Float16 h1h[4];
#pragma unroll
    for (int e = 0; e < 4; ++e) {
      float ig = acc1[0][e] + bia1[0];
      float fg = acc1[1][e] + bia1[1];
      float gg = acc1[2][e] + bia1[2];
      float og = acc1[3][e] + bia1[3];
      float cn = sigm_(fg) * c1[e] + sigm_(ig) * tanh_(gg);
      c1[e] = cn;
      float hn = sigm_(og) * tanh_(cn);
      h1h[e] = (_Float16)hn;
      out1[((size_t)(nb * RPB_ + (quad << 2) + e) * T_ + t) * H_ + col] = hn;
    }
    __syncthreads();  // #3
#pragma unroll
    for (int e = 0; e < 4; ++e)
      A1[(quad << 2) + e][N_ + col] = h1h[e];
    if (t + 1 < T_) {
      f32x4 s4 = *(const f32x4*)(scale + (t + 1) * N_ + sc);
      f32x4 h4 = *(const f32x4*)(shift + (t + 1) * N_ + sc);
      f16x4 hv;
#pragma unroll
      for (int e = 0; e < 4; ++e) hv[e] = (_Float16)fmaf(xn[e], s4[e], h4[e]);
      *(f16x4*)&A0[sr][sc] = hv;
    }
    __syncthreads();  // #4
  }
}

extern "C" void kernel_launch(void* const* d_in, const int* in_sizes, int n_in,
                              void* d_out, int out_size, void* d_ws, size_t ws_size,
                              hipStream_t stream) {
  const float* X = (const float*)d_in[0];
  const float* attnw = (const float*)d_in[1];
  const float* attnb = (const float*)d_in[2];
  const float* gamma = (const float*)d_in[3];
  const float* beta = (const float*)d_in[4];
  const float* Wih0 = (const float*)d_in[5];
  const float* Whh0 = (const float*)d_in[6];
  const float* bih0 = (const float*)d_in[7];
  const float* bhh0 = (const float*)d_in[8];
  const float* Wih1 = (const float*)d_in[9];
  const float* Whh1 = (const float*)d_in[10];
  const float* bih1 = (const float*)d_in[11];
  const float* bhh1 = (const float*)d_in[12];

  float* out0 = (float*)d_out;                    // X_tilde
  float* out1 = out0 + (size_t)B_ * T_ * N_;      // X_encoded

  // BN partials live in out1's region as scratch (67 MB < 268 MB); consumed by k3r
  // before k4 overwrites out1 (same stream -> ordered).
  float* psum = out1;
  float* psq = out1 + (size_t)KB_ * PSBLK_;

  float* ws = (float*)d_ws;
  float* scale = ws;                              // T*N
  float* shift = scale + T_ * N_;                 // T*N
  float* bpack = shift + T_ * N_;                 // 2*512
  _Float16* Wpack = (_Float16*)(bpack + 2 * G4_); // 2*512*256 f16 (16B-aligned)

  k0_prep<<<1024, 256, 0, stream>>>(Wih0, Whh0, bih0, bhh0, Wih1, Whh1, bih1, bhh1,
                                    Wpack, bpack);
  k12_fused<<<KB_, 256, 0, stream>>>(X, attnw, attnb, out0, psum, psq);
  k3r<<<T_, N_, 0, stream>>>(psum, psq, gamma, beta, scale, shift);
  k4_recur<<<NB_, 512, 0, stream>>>(out0, Wpack, bpack, scale, shift, out1);
}

// Round 6
// 1331.549 us; speedup vs baseline: 1.3165x; 1.0401x over previous
//
#include <hip/hip_runtime.h>
#include <cstdint>
#include <cstddef>

#define B_ 4096
#define T_ 128
#define N_ 128
#define H_ 128
#define G4_ 512       // 4*H
#define KC_ 256       // concat K = [x|h]
#define EPS_ 1e-5f

#define RPB_ 16       // batch rows per block (k4)
#define NB_ 256       // k4 blocks (one per CU)
#define W0K_ 128      // layer0 K-half staged in LDS (k = 0..127, the x-part)
#define W0P_ 136      // W0l LDS stride (f16)

#define KB2_ 256      // k12 blocks (one per CU)
#define ROWS2_ 16     // b-rows per k12 block

typedef _Float16 f16x8 __attribute__((ext_vector_type(8)));
typedef _Float16 f16x4 __attribute__((ext_vector_type(4)));
typedef float f32x4 __attribute__((ext_vector_type(4)));

__device__ __forceinline__ float sigm_(float x) { return 1.f / (1.f + __expf(-x)); }
__device__ __forceinline__ float tanh_(float x) {
  float ax = fabsf(x);
  float e = __expf(-2.f * ax);
  float t = (1.f - e) / (1.f + e);
  return copysignf(t, x);
}

// ---------------- K0: pack weights to f16 [2][512][256] = [Wih | Whh], combine biases
__global__ void k0_prep(const float* __restrict__ Wih0, const float* __restrict__ Whh0,
                        const float* __restrict__ bih0, const float* __restrict__ bhh0,
                        const float* __restrict__ Wih1, const float* __restrict__ Whh1,
                        const float* __restrict__ bih1, const float* __restrict__ bhh1,
                        _Float16* __restrict__ Wpack, float* __restrict__ bpack) {
  int idx = blockIdx.x * blockDim.x + threadIdx.x;
  if (idx < 2 * G4_ * KC_) {
    int k = idx & (KC_ - 1);
    int j = (idx >> 8) & (G4_ - 1);
    int l = idx >> 17;
    const float* Wih = l ? Wih1 : Wih0;
    const float* Whh = l ? Whh1 : Whh0;
    float v = (k < N_) ? Wih[j * N_ + k] : Whh[j * N_ + (k - N_)];
    Wpack[idx] = (_Float16)v;
  }
  if (idx < 2 * G4_) {
    int j = idx & (G4_ - 1);
    bpack[idx] = (idx >> 9) ? (bih1[j] + bhh1[j]) : (bih0[j] + bhh0[j]);
  }
}

// ---------------- K12 v2: fused alpha + X_tilde + BN partials, DOUBLE-BUFFERED.
// 256 blocks (1/CU) x 512 threads (8 waves), 16 b-rows/block, xs[2] 128 KB LDS.
// Per row: issue next row's global loads early (regs), compute current row
// (score -> softmax -> x_tilde), write staged regs to other buffer late.
// Thread (n = tid&127, tq = tid>>7) owns t in [tq*32, tq*32+32).
__global__ __launch_bounds__(512, 1) void k12_fused(
    const float* __restrict__ X, const float* __restrict__ attn_w,
    const float* __restrict__ attn_b, float* __restrict__ out0,
    float* __restrict__ psum, float* __restrict__ psq) {
  __shared__ float xs[2 * T_ * N_];  // 131072 B
  __shared__ float wx[T_];
  __shared__ float redS[4][N_];
  __shared__ float redM[8], redE[8];
  const int tid = threadIdx.x;   // 0..511
  const int blk = blockIdx.x;    // 0..255
  const int n = tid & 127;
  const int tq = tid >> 7;       // t-quarter 0..3
  const int wv = tid >> 6;       // wave 0..7
  const int row0 = blk * ROWS2_;
  if (tid < T_) wx[tid] = attn_w[2 * H_ + tid];
  const float ab = attn_b[0];

  float sum[32], sq[32];
#pragma unroll
  for (int i = 0; i < 32; ++i) { sum[i] = 0.f; sq[i] = 0.f; }

  // prologue: stage row 0 into buffer 0
  {
    const float* xb = X + (size_t)row0 * T_ * N_;
#pragma unroll
    for (int i = 0; i < 8; ++i) {
      int fi = ((i << 9) + tid) << 2;
      *(f32x4*)&xs[fi] = *(const f32x4*)&xb[fi];
    }
  }

  int buf = 0;
  for (int rb = 0; rb < ROWS2_; ++rb) {
    __syncthreads();  // buf's staging visible; prior row's LDS readers done
    const float* xcur = xs + (buf << 14);

    // issue next row's loads NOW (covered by this row's whole compute phase)
    f32x4 stg[8];
    if (rb + 1 < ROWS2_) {
      const float* xb1 = X + (size_t)(row0 + rb + 1) * T_ * N_;
#pragma unroll
      for (int i = 0; i < 8; ++i)
        stg[i] = *(const f32x4*)&xb1[((i << 9) + tid) << 2];
    }

    // score: partial column-dot over this thread's t-quarter
    float s = 0.f;
#pragma unroll
    for (int tt = 0; tt < 32; ++tt) {
      int t = (tq << 5) + tt;
      s = fmaf(xcur[t * N_ + n], wx[t], s);
    }
    redS[tq][n] = s;
    __syncthreads();
    s = redS[0][n] + redS[1][n] + redS[2][n] + redS[3][n] + ab;

    // softmax over n (waves duplicate n-halves; max idempotent, sum uses waves 0+1)
    float m = s;
#pragma unroll
    for (int off = 32; off >= 1; off >>= 1) m = fmaxf(m, __shfl_xor(m, off));
    if ((tid & 63) == 0) redM[wv] = m;
    __syncthreads();
    m = fmaxf(fmaxf(fmaxf(redM[0], redM[1]), fmaxf(redM[2], redM[3])),
              fmaxf(fmaxf(redM[4], redM[5]), fmaxf(redM[6], redM[7])));
    float e = __expf(s - m);
    float sm = e;
#pragma unroll
    for (int off = 32; off >= 1; off >>= 1) sm += __shfl_xor(sm, off);
    if ((tid & 63) == 0) redE[wv] = sm;
    __syncthreads();
    sm = redE[0] + redE[1];
    const float alpha = e / sm;

    // write staged regs to the other buffer (compiler places waitcnt here, late)
    if (rb + 1 < ROWS2_) {
      float* xnx = xs + ((buf ^ 1) << 14);
#pragma unroll
      for (int i = 0; i < 8; ++i)
        *(f32x4*)&xnx[((i << 9) + tid) << 2] = stg[i];
    }

    // x_tilde + stats (fully unrolled -> static reg indexing)
    const size_t b = (size_t)(row0 + rb);
#pragma unroll
    for (int tt = 0; tt < 32; ++tt) {
      int t = (tq << 5) + tt;
      float v = alpha * xcur[t * N_ + n];
      sum[tt] += v;
      sq[tt] += v * v;
      out0[(b * T_ + t) * N_ + n] = v;
    }
    buf ^= 1;
  }

  // write partials: ps[blk][t][n]
  float* pbs = psum + ((size_t)blk << 14) + (tq << 5) * N_ + n;
  float* pbq = psq + ((size_t)blk << 14) + (tq << 5) * N_ + n;
#pragma unroll
  for (int tt = 0; tt < 32; ++tt) {
    pbs[tt * N_] = sum[tt];
    pbq[tt * N_] = sq[tt];
  }
}

// ---------------- K3r: reduce partials over 256 blocks -> per-(t,n) scale/shift
__global__ void k3r(const float* __restrict__ psum, const float* __restrict__ psq,
                    const float* __restrict__ gamma, const float* __restrict__ beta,
                    float* __restrict__ scale, float* __restrict__ shift) {
  __shared__ float rs[2][N_], rq[2][N_];
  const int t = blockIdx.x;     // 0..127
  const int tid = threadIdx.x;  // 0..255
  const int n = tid & 127;
  const int hb = tid >> 7;      // block-range half
  const size_t off = (size_t)t * N_ + n;
  float s = 0.f, q = 0.f;
#pragma unroll 4
  for (int i = 0; i < 128; ++i) {
    size_t o = ((size_t)((hb << 7) + i) << 14) + off;
    s += psum[o];
    q += psq[o];
  }
  rs[hb][n] = s;
  rq[hb][n] = q;
  __syncthreads();
  if (hb == 0) {
    s = rs[0][n] + rs[1][n];
    q = rq[0][n] + rq[1][n];
    float mean = s * (1.f / B_);
    float var = q * (1.f / B_) - mean * mean;
    float rstd = rsqrtf(var + EPS_);
    float g = gamma[n];
    scale[t * N_ + n] = rstd * g;
    shift[t * N_ + n] = beta[n] - mean * rstd * g;
  }
}

// ---------------- K4: 2-layer LSTM recurrence — EXACT v2 (proven 756-765 µs).
// 256 blocks x 16 rows, 8 waves. Wave w owns output cols [w*16,w*16+16), all 4 gates
// (register-only activations). Layer-1 weights: plain loads, compiler remat/pipelines
// from L2 (empirically faster than forced residency). W0 x-half in LDS; h-half inline.
__global__ __launch_bounds__(512, 2) void k4_recur(
    const float* __restrict__ xt /* X_tilde */, const _Float16* __restrict__ Wpack,
    const float* __restrict__ bpack, const float* __restrict__ scale,
    const float* __restrict__ shift, float* __restrict__ out1) {
  __shared__ _Float16 W0l[G4_][W0P_];  // 139264 B
  __shared__ _Float16 A0[RPB_][264];   // [xb | h0], 8448 B
  __shared__ _Float16 A1[RPB_][264];   // [h0n | h1], 8448 B   (total 156160 B)

  const int tid = threadIdx.x;
  const int w = tid >> 6;
  const int lane = tid & 63;
  const int quad = lane >> 4;
  const int l16 = lane & 15;
  const int nb = blockIdx.x;
  const int col = (w << 4) + l16;

  {
    const _Float16* src = Wpack + (size_t)tid * KC_;
#pragma unroll
    for (int kk = 0; kk < W0K_; kk += 8)
      *(f16x8*)&W0l[tid][kk] = *(const f16x8*)&src[kk];
  }

  f16x8 w1[4][8];
#pragma unroll
  for (int g = 0; g < 4; ++g) {
    const _Float16* src = Wpack + (size_t)(G4_ + (g << 7) + col) * KC_ + (quad << 3);
#pragma unroll
    for (int kb = 0; kb < 8; ++kb) w1[g][kb] = *(const f16x8*)&src[kb << 5];
  }

  float bia0[4], bia1[4];
#pragma unroll
  for (int g = 0; g < 4; ++g) {
    bia0[g] = bpack[(g << 7) + col];
    bia1[g] = bpack[G4_ + (g << 7) + col];
  }

  float c0[4], c1[4];
#pragma unroll
  for (int e = 0; e < 4; ++e) { c0[e] = 0.f; c1[e] = 0.f; }

  const int sr = tid >> 5;
  const int sc = (tid & 31) << 2;
  const size_t browbase = (size_t)(nb * RPB_ + sr) * T_;

  {
    f32x4 xv = *(const f32x4*)(xt + (browbase + 0) * N_ + sc);
    f32x4 s4 = *(const f32x4*)(scale + sc);
    f32x4 h4 = *(const f32x4*)(shift + sc);
    f16x4 hv;
#pragma unroll
    for (int e = 0; e < 4; ++e) hv[e] = (_Float16)fmaf(xv[e], s4[e], h4[e]);
    *(f16x4*)&A0[sr][sc] = hv;
    f16x4 z = {};
    *(f16x4*)&A0[sr][N_ + sc] = z;
    *(f16x4*)&A1[sr][N_ + sc] = z;
  }
  __syncthreads();

  for (int t = 0; t < T_; ++t) {
    f32x4 xn = {};
    if (t + 1 < T_) xn = *(const f32x4*)(xt + (browbase + t + 1) * N_ + sc);

    f32x4 acc[4] = {};
#pragma unroll
    for (int kb = 0; kb < 8; ++kb) {
      f16x8 a = *(const f16x8*)&A0[l16][(kb << 5) + (quad << 3)];
      if (kb < 4) {
#pragma unroll
        for (int g = 0; g < 4; ++g) {
          f16x8 bf = *(const f16x8*)&W0l[(g << 7) + col][(kb << 5) + (quad << 3)];
          acc[g] = __builtin_amdgcn_mfma_f32_16x16x32_f16(a, bf, acc[g], 0, 0, 0);
        }
      } else {
#pragma unroll
        for (int g = 0; g < 4; ++g) {
          f16x8 bf = *(const f16x8*)(Wpack + (size_t)((g << 7) + col) * KC_ +
                                     (kb << 5) + (quad << 3));
          acc[g] = __builtin_amdgcn_mfma_f32_16x16x32_f16(a, bf, acc[g], 0, 0, 0);
        }
      }
    }

    _Float16 h0h[4];
#pragma unroll
    for (int e = 0; e < 4; ++e) {
      float ig = acc[0][e] + bia0[0];
      float fg = acc[1][e] + bia0[1];
      float gg = acc[2][e] + bia0[2];
      float og = acc[3][e] + bia0[3];
      float cn = sigm_(fg) * c0[e] + sigm_(ig) * tanh_(gg);
      c0[e] = cn;
      h0h[e] = (_Float16)(sigm_(og) * tanh_(cn));
    }
    __syncthreads();  // #1
#pragma unroll
    for (int e = 0; e < 4; ++e) {
      A0[(quad << 2) + e][N_ + col] = h0h[e];
      A1[(quad << 2) + e][col] = h0h[e];
    }
    __syncthreads();  // #2

    f16x8 a1[8];
#pragma unroll
    for (int kb = 0; kb < 4; ++kb) {
      a1[kb] = *(const f16x8*)&A1[l16][(kb << 5) + (quad << 3)];
      a1[4 + kb] = *(const f16x8*)&A1[l16][128 + (kb << 5) + (quad << 3)];
    }
    f32x4 acc1[4] = {};
#pragma unroll
    for (int kb = 0; kb < 8; ++kb) {
#pragma unroll
      for (int g = 0; g < 4; ++g)
        acc1[g] = __builtin_amdgcn_mfma_f32_16x16x32_f16(a1[kb], w1[g][kb], acc1[g], 0, 0, 0);
    }

    _Float16 h1h[4];
#pragma unroll
    for (int e = 0; e < 4; ++e) {
      float ig = acc1[0][e] + bia1[0];
      float fg = acc1[1][e] + bia1[1];
      float gg = acc1[2][e] + bia1[2];
      float og = acc1[3][e] + bia1[3];
      float cn = sigm_(fg) * c1[e] + sigm_(ig) * tanh_(gg);
      c1[e] = cn;
      float hn = sigm_(og) * tanh_(cn);
      h1h[e] = (_Float16)hn;
      out1[((size_t)(nb * RPB_ + (quad << 2) + e) * T_ + t) * H_ + col] = hn;
    }
    __syncthreads();  // #3
#pragma unroll
    for (int e = 0; e < 4; ++e)
      A1[(quad << 2) + e][N_ + col] = h1h[e];
    if (t + 1 < T_) {
      f32x4 s4 = *(const f32x4*)(scale + (t + 1) * N_ + sc);
      f32x4 h4 = *(const f32x4*)(shift + (t + 1) * N_ + sc);
      f16x4 hv;
#pragma unroll
      for (int e = 0; e < 4; ++e) hv[e] = (_Float16)fmaf(xn[e], s4[e], h4[e]);
      *(f16x4*)&A0[sr][sc] = hv;
    }
    __syncthreads();  // #4
  }
}

extern "C" void kernel_launch(void* const* d_in, const int* in_sizes, int n_in,
                              void* d_out, int out_size, void* d_ws, size_t ws_size,
                              hipStream_t stream) {
  const float* X = (const float*)d_in[0];
  const float* attnw = (const float*)d_in[1];
  const float* attnb = (const float*)d_in[2];
  const float* gamma = (const float*)d_in[3];
  const float* beta = (const float*)d_in[4];
  const float* Wih0 = (const float*)d_in[5];
  const float* Whh0 = (const float*)d_in[6];
  const float* bih0 = (const float*)d_in[7];
  const float* bhh0 = (const float*)d_in[8];
  const float* Wih1 = (const float*)d_in[9];
  const float* Whh1 = (const float*)d_in[10];
  const float* bih1 = (const float*)d_in[11];
  const float* bhh1 = (const float*)d_in[12];

  float* out0 = (float*)d_out;                    // X_tilde
  float* out1 = out0 + (size_t)B_ * T_ * N_;      // X_encoded

  // BN partials live in out1's region as scratch (32 MB < 268 MB); consumed by k3r
  // before k4 overwrites out1 (same stream -> ordered).
  float* psum = out1;
  float* psq = out1 + ((size_t)KB2_ << 14);

  float* ws = (float*)d_ws;
  float* scale = ws;                              // T*N
  float* shift = scale + T_ * N_;                 // T*N
  float* bpack = shift + T_ * N_;                 // 2*512
  _Float16* Wpack = (_Float16*)(bpack + 2 * G4_); // 2*512*256 f16 (16B-aligned)

  k0_prep<<<1024, 256, 0, stream>>>(Wih0, Whh0, bih0, bhh0, Wih1, Whh1, bih1, bhh1,
                                    Wpack, bpack);
  k12_fused<<<KB2_, 512, 0, stream>>>(X, attnw, attnb, out0, psum, psq);
  k3r<<<T_, 256, 0, stream>>>(psum, psq, gamma, beta, scale, shift);
  k4_recur<<<NB_, 512, 0, stream>>>(out0, Wpack, bpack, scale, shift, out1);
}